// Round 4
// baseline (238.220 us; speedup 1.0000x reference)
//
#include <hip/hip_runtime.h>
#include <cstdint>
#include <cstddef>

#define B_N   64
#define DM    256
#define PP    1024
#define DQ    512
#define DV    256

typedef __attribute__((ext_vector_type(8))) short short8;
typedef __attribute__((ext_vector_type(4))) float floatx4;
typedef unsigned short u16;
typedef unsigned int   u32;

__device__ __forceinline__ float bf2f(u16 u) {
  u32 x = ((u32)u) << 16;
  return __builtin_bit_cast(float, x);
}
__device__ __forceinline__ u16 f2bf(float f) {
  u32 x = __builtin_bit_cast(u32, f);
  u32 r = (x + 0x7fffu + ((x >> 16) & 1u)) >> 16;
  return (u16)r;
}

__device__ __forceinline__ float red16_max(float v) {
#pragma unroll
  for (int m = 1; m < 16; m <<= 1) v = fmaxf(v, __shfl_xor(v, m));
  return v;
}
__device__ __forceinline__ float red16_sum(float v) {
#pragma unroll
  for (int m = 1; m < 16; m <<= 1) v += __shfl_xor(v, m);
  return v;
}

// ---------------------------------------------------------------------------
// x (B, C=256, P=1024) fp32  ->  xbt (B, P, C) bf16  +  per-(b,c) partial sums
// ---------------------------------------------------------------------------
__global__ __launch_bounds__(256) void k_transpose(const float* __restrict__ x,
                                                   u16* __restrict__ xbt,
                                                   float* __restrict__ psum) {
  int bid = blockIdx.x;
  int b = bid >> 6, t = bid & 63;
  int c0 = (t >> 4) << 6;
  int p0 = (t & 15) << 6;
  __shared__ float tile[64][65];
  int tid = threadIdx.x;
  int lo = tid & 63, hi = tid >> 6;
  const float* xp = x + ((size_t)b * DM + c0) * PP + p0;
#pragma unroll
  for (int rr = 0; rr < 16; ++rr) {
    int c = rr * 4 + hi;
    tile[c][lo] = xp[(size_t)c * PP + lo];
  }
  __syncthreads();
  if (tid < 64) {
    float s = 0.f;
#pragma unroll
    for (int j = 0; j < 64; ++j) s += tile[tid][j];
    psum[((size_t)b * DM + c0 + tid) * 16 + (t & 15)] = s;
  }
  u16* op = xbt + ((size_t)b * PP + p0) * DM + c0;
#pragma unroll
  for (int rr = 0; rr < 16; ++rr) {
    int p = rr * 4 + hi;
    op[(size_t)p * DM + lo] = f2bf(tile[lo][p]);
  }
}

__global__ __launch_bounds__(256) void k_xbar(const float* __restrict__ psum,
                                              float* __restrict__ xbar) {
  int i = blockIdx.x * 256 + threadIdx.x;
  const float* p = psum + (size_t)i * 16;
  float s = 0.f;
#pragma unroll
  for (int j = 0; j < 16; ++j) s += p[j];
  xbar[i] = s;
}

__global__ __launch_bounds__(256) void k_wconv(const float* __restrict__ q_w,
                                               const float* __restrict__ k_w,
                                               u16* __restrict__ q_wb,
                                               u16* __restrict__ k_wb) {
  int i = blockIdx.x * 256 + threadIdx.x;
  q_wb[i] = f2bf(q_w[i]);
  k_wb[i] = f2bf(k_w[i]);
}

// ---------------------------------------------------------------------------
// Unified NT GEMM, 128x128 tile, BK=64, XOR-swizzled LDS, double-buffered
// prefetch staging with counted vmcnt (T3/T4-minimum): next tile's
// global_load_lds stay in flight across raw s_barriers; vmcnt(8) in loop,
// vmcnt(0) only for the last tile.
// ---------------------------------------------------------------------------
#define MODE_K   0
#define MODE_Q   1
#define MODE_OUT 2

template<int MODE>
__global__ __launch_bounds__(256) void k_gemm(
    const u16* __restrict__ A, long sA,
    const u16* __restrict__ Bm, long sB,
    int N, int K,
    const float* __restrict__ bias_gm,   // MODE_K: k_b
    const float* __restrict__ bias_gn,   // MODE_Q: q_b
    void* __restrict__ out0, long sOut, int ldo,
    float* __restrict__ aux0,            // K: kpart(float2), Q: qpart, OUT: colscale
    float* __restrict__ aux1,            // K: kcen
    const float* __restrict__ obias)     // OUT: per (b,gm)
{
  int b = blockIdx.y;
  int ntn = N >> 7;
  int tm = blockIdx.x / ntn, tn = blockIdx.x % ntn;
  const u16* Ab = A + (size_t)b * sA + ((size_t)(tm << 7)) * K;
  const u16* Bb = Bm + (size_t)b * sB + ((size_t)(tn << 7)) * K;
  __shared__ u16 As[2][128 * 64];   // 2 x 16 KB
  __shared__ u16 Bs[2][128 * 64];   // 2 x 16 KB
  int tid = threadIdx.x;
  int lane = tid & 63, wid = tid >> 6;
  int wr = wid >> 1, wc = wid & 1;
  int rl = lane & 15, hi = lane >> 4;

  floatx4 acc[4][4];
#pragma unroll
  for (int m = 0; m < 4; ++m)
#pragma unroll
    for (int n = 0; n < 4; ++n) acc[m][n] = (floatx4){0.f, 0.f, 0.f, 0.f};

  // stage one 128x64 A-tile + B-tile into buffer `buf` (8 loads per wave)
  auto stage = [&](int buf, int k0) {
#pragma unroll
    for (int j = 0; j < 4; ++j) {
      int ch = j * 256 + tid;
      int row = ch >> 3;
      int sk = (((ch & 7) ^ (row & 7)) << 3);   // pre-swizzled source chunk
      __builtin_amdgcn_global_load_lds(
          (const __attribute__((address_space(1))) void*)(Ab + (size_t)row * K + k0 + sk),
          (__attribute__((address_space(3))) void*)(&As[buf][ch * 8]), 16, 0, 0);
      __builtin_amdgcn_global_load_lds(
          (const __attribute__((address_space(1))) void*)(Bb + (size_t)row * K + k0 + sk),
          (__attribute__((address_space(3))) void*)(&Bs[buf][ch * 8]), 16, 0, 0);
    }
  };

  auto compute = [&](int buf) {
#pragma unroll
    for (int kk = 0; kk < 64; kk += 32) {
      int c0 = (kk >> 3) + hi;
      short8 af[4], bfr[4];
#pragma unroll
      for (int m = 0; m < 4; ++m) {
        int ra = wr * 64 + m * 16 + rl;
        af[m] = *(const short8*)(&As[buf][ra * 64 + ((c0 ^ (ra & 7)) << 3)]);
      }
#pragma unroll
      for (int n = 0; n < 4; ++n) {
        int rb = wc * 64 + n * 16 + rl;
        bfr[n] = *(const short8*)(&Bs[buf][rb * 64 + ((c0 ^ (rb & 7)) << 3)]);
      }
#pragma unroll
      for (int m = 0; m < 4; ++m)
#pragma unroll
        for (int n = 0; n < 4; ++n)
          acc[m][n] = __builtin_amdgcn_mfma_f32_16x16x32_bf16(af[m], bfr[n], acc[m][n], 0, 0, 0);
    }
  };

  int NT = K >> 6;
  stage(0, 0);
  for (int t = 0; t < NT - 1; ++t) {
    int cur = t & 1;
    stage(cur ^ 1, (t + 1) << 6);                 // prefetch next tile
    asm volatile("s_waitcnt vmcnt(8)" ::: "memory");  // cur's 8 loads done; next's stay in flight
    __builtin_amdgcn_s_barrier();
    compute(cur);
    __builtin_amdgcn_s_barrier();                 // all reads of buf[cur] done before t+1 overwrites
  }
  asm volatile("s_waitcnt vmcnt(0)" ::: "memory");
  __builtin_amdgcn_s_barrier();
  compute((NT - 1) & 1);

  int gmbase = (tm << 7) + wr * 64;
  int gnbase = (tn << 7) + wc * 64;

  if (MODE == MODE_K) {
    if (tn == 3 || tn == 4) {
#pragma unroll
      for (int n = 0; n < 4; ++n) {
        int gn = gnbase + n * 16 + rl;
        int j = (gn == 495) ? 0 : (gn == 496) ? 1 : (gn == 527) ? 2 : (gn == 528) ? 3 : -1;
        if (j >= 0) {
#pragma unroll
          for (int m = 0; m < 4; ++m)
#pragma unroll
            for (int r = 0; r < 4; ++r) {
              int gm = gmbase + m * 16 + hi * 4 + r;
              aux1[((size_t)(b * 512) + gm) * 4 + j] = acc[m][n][r] + bias_gm[gm];
            }
        }
      }
    }
    float2* kp = (float2*)aux0;
#pragma unroll
    for (int m = 0; m < 4; ++m)
#pragma unroll
      for (int r = 0; r < 4; ++r) {
        int gm = gmbase + m * 16 + hi * 4 + r;
        float kb = bias_gm[gm];
        float v0 = acc[m][0][r] + kb, v1 = acc[m][1][r] + kb;
        float v2 = acc[m][2][r] + kb, v3 = acc[m][3][r] + kb;
        float mx = fmaxf(fmaxf(v0, v1), fmaxf(v2, v3));
        mx = red16_max(mx);
        float se = __expf(v0 - mx) + __expf(v1 - mx) + __expf(v2 - mx) + __expf(v3 - mx);
        se = red16_sum(se);
        if (rl == 0)
          kp[((size_t)(b * 512) + gm) * 16 + tn * 2 + wc] = make_float2(mx, se);
      }
  }

  if (MODE == MODE_Q) {
    float qb[4];
#pragma unroll
    for (int n = 0; n < 4; ++n) qb[n] = bias_gn[gnbase + n * 16 + rl];
    u16* qe = (u16*)out0;
#pragma unroll
    for (int m = 0; m < 4; ++m)
#pragma unroll
      for (int r = 0; r < 4; ++r) {
        int gm = gmbase + m * 16 + hi * 4 + r;
        float rs = 0.f;
#pragma unroll
        for (int n = 0; n < 4; ++n) {
          float e = __expf(acc[m][n][r] + qb[n]);
          rs += e;
          qe[(size_t)b * sOut + (size_t)gm * ldo + gnbase + n * 16 + rl] = f2bf(e);
        }
        rs = red16_sum(rs);
        if (rl == 0)
          aux0[((size_t)(b * 1024) + gm) * 8 + tn * 2 + wc] = rs;
      }
  }

  if (MODE == MODE_OUT) {
    float cs[4];
#pragma unroll
    for (int n = 0; n < 4; ++n) cs[n] = aux0[b * 1024 + gnbase + n * 16 + rl];
    float* op = (float*)out0;
#pragma unroll
    for (int m = 0; m < 4; ++m)
#pragma unroll
      for (int r = 0; r < 4; ++r) {
        int gm = gmbase + m * 16 + hi * 4 + r;
        float ob = obias[b * 256 + gm];
#pragma unroll
        for (int n = 0; n < 4; ++n)
          op[(size_t)b * sOut + (size_t)gm * ldo + gnbase + n * 16 + rl] =
              acc[m][n][r] * cs[n] + ob;
      }
  }
}

// ---------------------------------------------------------------------------
// Combine K partials: per (b,o) global max + expsum; kcexp; S[b]
// ---------------------------------------------------------------------------
__global__ __launch_bounds__(512) void k_combine(const float2* __restrict__ kpart,
                                                 const float* __restrict__ kcen,
                                                 float* __restrict__ kcexp,
                                                 float* __restrict__ Sb) {
  int b = blockIdx.x, o = threadIdx.x;
  const float2* kp = kpart + ((size_t)(b * 512) + o) * 16;
  float mx = kp[0].x;
#pragma unroll
  for (int t = 1; t < 16; ++t) mx = fmaxf(mx, kp[t].x);
  float se = 0.f;
#pragma unroll
  for (int t = 0; t < 16; ++t) se += kp[t].y * __expf(kp[t].x - mx);
  const float* kc = kcen + ((size_t)(b * 512) + o) * 4;
#pragma unroll
  for (int j = 0; j < 4; ++j)
    kcexp[((size_t)(b * 512) + o) * 4 + j] = __expf(kc[j] - mx);
  __shared__ float sd[512];
  sd[o] = se; __syncthreads();
  for (int k = 256; k > 0; k >>= 1) { if (o < k) sd[o] += sd[o + k]; __syncthreads(); }
  if (o == 0) Sb[b] = sd[0];
}

__global__ __launch_bounds__(256) void k_qscale(const float* __restrict__ qpart,
                                                float* __restrict__ colscale) {
  int i = blockIdx.x * 256 + threadIdx.x;
  const float4* p = (const float4*)(qpart + (size_t)i * 8);
  float4 a = p[0], c = p[1];
  colscale[i] = 1.f / (a.x + a.y + a.z + a.w + c.x + c.y + c.z + c.w);
}

__global__ __launch_bounds__(256) void k_vc(const u16* __restrict__ xbt,
                                            const float* __restrict__ v_w,
                                            const float* __restrict__ v_b,
                                            float* __restrict__ Vc) {
  int b = blockIdx.x, vo = threadIdx.x;
  const int cp[4] = {495, 496, 527, 528};
  float acc[4];
  float vb = v_b[vo];
#pragma unroll
  for (int j = 0; j < 4; ++j) acc[j] = vb;
  for (int cc = 0; cc < 256; cc += 4) {
    float4 w = *(const float4*)(v_w + (size_t)vo * 256 + cc);
#pragma unroll
    for (int j = 0; j < 4; ++j) {
      const u16* xr = xbt + ((size_t)b * PP + cp[j]) * DM + cc;
      acc[j] += w.x * bf2f(xr[0]) + w.y * bf2f(xr[1]) + w.z * bf2f(xr[2]) + w.w * bf2f(xr[3]);
    }
  }
#pragma unroll
  for (int j = 0; j < 4; ++j) Vc[((size_t)b * 256 + vo) * 4 + j] = acc[j];
}

__global__ __launch_bounds__(256) void k_kvp(const float* __restrict__ kcexp,
                                             const float* __restrict__ Vc,
                                             const float* __restrict__ S,
                                             float* __restrict__ KVp) {
  int b = blockIdx.x >> 3, h = blockIdx.x & 7;
  float inv = 0.25f / S[b];
  int tid = threadIdx.x;
#pragma unroll
  for (int j = 0; j < 8; ++j) {
    int idx = j * 256 + tid;
    int q = idx >> 5, v = idx & 31;
    const float* kc = kcexp + ((size_t)b * 512 + h * 64 + q) * 4;
    const float* vv = Vc + ((size_t)b * 256 + h * 32 + v) * 4;
    KVp[(((size_t)(b * 8 + h) * 64 + q) * 32) + v] =
        inv * (kc[0] * vv[0] + kc[1] * vv[1] + kc[2] * vv[2] + kc[3] * vv[3]);
  }
}

__global__ __launch_bounds__(256) void k_lnbias(const float* __restrict__ xbar,
                                                const float* __restrict__ bias_w,
                                                const float* __restrict__ bias_b,
                                                const float* __restrict__ ln_g,
                                                const float* __restrict__ ln_b,
                                                const float* __restrict__ uni_w,
                                                const float* __restrict__ uni_b,
                                                float* __restrict__ obias) {
  int b = blockIdx.x, o = threadIdx.x;
  const float* xb = xbar + (size_t)b * 256;
  float acc = 0.f;
  for (int cc = 0; cc < 256; cc += 4) {
    float4 w = *(const float4*)(bias_w + (size_t)o * 256 + cc);
    acc += w.x * xb[cc] + w.y * xb[cc + 1] + w.z * xb[cc + 2] + w.w * xb[cc + 3];
  }
  float bf_ = acc * (1.f / 1024.f) + bias_b[o];
  __shared__ float sd[256];
  sd[o] = bf_; __syncthreads();
  for (int k = 128; k > 0; k >>= 1) { if (o < k) sd[o] += sd[o + k]; __syncthreads(); }
  float mu = sd[0] / 256.f; __syncthreads();
  sd[o] = bf_ * bf_; __syncthreads();
  for (int k = 128; k > 0; k >>= 1) { if (o < k) sd[o] += sd[o + k]; __syncthreads(); }
  float var = sd[0] / 256.f - mu * mu; __syncthreads();
  float nb = (bf_ - mu) * rsqrtf(var + 1e-5f) * ln_g[o] + ln_b[o];
  sd[o] = nb; __syncthreads();
  float ob = uni_b[o];
  for (int vo = 0; vo < 256; ++vo) ob += uni_w[(size_t)o * 256 + vo] * sd[vo];
  obias[(size_t)b * 256 + o] = ob;
}

// Wc[b][m][h*64+q] = sum_v uni_w[m][h*32+v] * KVp[b][h][q][v]
__global__ __launch_bounds__(256) void k_wc(const float* __restrict__ KVp,
                                            const float* __restrict__ uni_w,
                                            u16* __restrict__ Wc) {
  int b = blockIdx.x >> 3;
  int h = blockIdx.x & 7;
  __shared__ float kv[64 * 32];
  int tid = threadIdx.x;
  const float* src = KVp + (size_t)b * 16384 + (size_t)h * 2048;
#pragma unroll
  for (int j = 0; j < 8; ++j) kv[j * 256 + tid] = src[j * 256 + tid];
  __syncthreads();

  int m = tid;
  float uw[32];
  const float* uwp = uni_w + (size_t)m * 256 + h * 32;
#pragma unroll
  for (int v = 0; v < 32; v += 4) {
    float4 w = *(const float4*)(uwp + v);
    uw[v] = w.x; uw[v + 1] = w.y; uw[v + 2] = w.z; uw[v + 3] = w.w;
  }

  union { uint4 o4[8]; u16 os[64]; } ob;
#pragma unroll
  for (int q = 0; q < 64; ++q) {
    const float* kp = kv + q * 32;
    float s = 0.f;
#pragma unroll
    for (int v = 0; v < 32; ++v) s += uw[v] * kp[v];
    ob.os[q] = f2bf(s);
  }
  uint4* dst = (uint4*)(Wc + ((size_t)(b * 256 + m)) * 512 + h * 64);
#pragma unroll
  for (int j = 0; j < 8; ++j) dst[j] = ob.o4[j];
}

// ---------------------------------------------------------------------------
extern "C" void kernel_launch(void* const* d_in, const int* in_sizes, int n_in,
                              void* d_out, int out_size, void* d_ws, size_t ws_size,
                              hipStream_t stream) {
  const float* x      = (const float*)d_in[0];
  const float* q_w    = (const float*)d_in[1];
  const float* q_b    = (const float*)d_in[2];
  const float* k_w    = (const float*)d_in[3];
  const float* k_b    = (const float*)d_in[4];
  const float* v_w    = (const float*)d_in[5];
  const float* v_b    = (const float*)d_in[6];
  const float* bias_w = (const float*)d_in[7];
  const float* bias_b = (const float*)d_in[8];
  const float* ln_g   = (const float*)d_in[9];
  const float* ln_b   = (const float*)d_in[10];
  const float* uni_w  = (const float*)d_in[11];
  const float* uni_b  = (const float*)d_in[12];

  char* ws = (char*)d_ws;
  size_t off = 0;
  auto alloc = [&](size_t bytes) {
    void* p = ws + off;
    off = (off + bytes + 255) & ~(size_t)255;
    return p;
  };
  u16*   xbt   = (u16*)  alloc(64ull * 1024 * 256 * 2);   // x^T bf16
  u16*   qexp  = (u16*)  alloc(64ull * 1024 * 512 * 2);   // exp(Q^T) bf16
  u16*   wcb   = (u16*)  alloc(64ull * 256 * 512 * 2);    // folded uni_w∘KVp
  u16*   q_wb  = (u16*)  alloc(131072ull * 2);
  u16*   k_wb  = (u16*)  alloc(131072ull * 2);
  float* psum  = (float*)alloc(64ull * 256 * 16 * 4);
  float* xbar  = (float*)alloc(64ull * 256 * 4);
  float* kpart = (float*)alloc(32768ull * 16 * 8);        // float2 per (row, tn, wc)
  float* kcen  = (float*)alloc(32768ull * 4 * 4);
  float* qpart = (float*)alloc(65536ull * 8 * 4);
  float* cscal = (float*)alloc(65536ull * 4);
  float* Sb    = (float*)alloc(64ull * 4);
  float* kcexp = (float*)alloc(64ull * 512 * 4 * 4);
  float* vc    = (float*)alloc(64ull * 256 * 4 * 4);
  float* kvp   = (float*)alloc(64ull * 8 * 64 * 32 * 4);
  float* obias = (float*)alloc(64ull * 256 * 4);
  (void)ws_size; (void)in_sizes; (void)n_in; (void)out_size;

  k_wconv<<<512, 256, 0, stream>>>(q_w, k_w, q_wb, k_wb);
  k_transpose<<<4096, 256, 0, stream>>>(x, xbt, psum);
  k_xbar<<<64, 256, 0, stream>>>(psum, xbar);

  // K projection + fused stats: M=512(o), N=1024(p), K=256  — no C write
  k_gemm<MODE_K><<<dim3(32, 64), 256, 0, stream>>>(
      k_wb, 0L, xbt, 262144L, 1024, 256,
      k_b, nullptr, nullptr, 0L, 0, kpart, kcen, nullptr);
  // Q projection + fused exp: M=1024(p), N=512(o), K=256  — qexp bf16
  k_gemm<MODE_Q><<<dim3(32, 64), 256, 0, stream>>>(
      xbt, 262144L, q_wb, 0L, 512, 256,
      nullptr, q_b, (void*)qexp, 524288L, 512, qpart, nullptr, nullptr);

  k_combine<<<64, 512, 0, stream>>>((const float2*)kpart, kcen, kcexp, Sb);
  k_qscale<<<256, 256, 0, stream>>>(qpart, cscal);
  k_vc<<<64, 256, 0, stream>>>(xbt, v_w, v_b, vc);
  k_kvp<<<512, 256, 0, stream>>>(kcexp, vc, Sb, kvp);
  k_lnbias<<<64, 256, 0, stream>>>(xbar, bias_w, bias_b, ln_g, ln_b, uni_w, uni_b, obias);
  k_wc<<<512, 256, 0, stream>>>(kvp, uni_w, wcb);

  // Final GEMM: out[b][m][p] = (Wc @ Qexp^T) * colscale[p] + obias[m]
  k_gemm<MODE_OUT><<<dim3(16, 64), 256, 0, stream>>>(
      wcb, 131072L, qexp, 524288L, 1024, 512,
      nullptr, nullptr, d_out, 262144L, 1024, cscal, nullptr, obias);
}

// Round 5
// 212.903 us; speedup vs baseline: 1.1189x; 1.1189x over previous
//
#include <hip/hip_runtime.h>
#include <cstdint>
#include <cstddef>

#define B_N   64
#define DM    256
#define PP    1024
#define DQ    512
#define DV    256

typedef __attribute__((ext_vector_type(8))) short short8;
typedef __attribute__((ext_vector_type(4))) float floatx4;
typedef unsigned short u16;
typedef unsigned int   u32;

__device__ __forceinline__ float bf2f(u16 u) {
  u32 x = ((u32)u) << 16;
  return __builtin_bit_cast(float, x);
}
__device__ __forceinline__ u16 f2bf(float f) {
  u32 x = __builtin_bit_cast(u32, f);
  u32 r = (x + 0x7fffu + ((x >> 16) & 1u)) >> 16;
  return (u16)r;
}

__device__ __forceinline__ float red16_max(float v) {
#pragma unroll
  for (int m = 1; m < 16; m <<= 1) v = fmaxf(v, __shfl_xor(v, m));
  return v;
}
__device__ __forceinline__ float red16_sum(float v) {
#pragma unroll
  for (int m = 1; m < 16; m <<= 1) v += __shfl_xor(v, m);
  return v;
}

// ---------------------------------------------------------------------------
// x (B, C=256, P=1024) fp32  ->  xbt (B, P, C) bf16  +  per-(b,c) partial sums
// ---------------------------------------------------------------------------
__global__ __launch_bounds__(256) void k_transpose(const float* __restrict__ x,
                                                   u16* __restrict__ xbt,
                                                   float* __restrict__ psum) {
  int bid = blockIdx.x;
  int b = bid >> 6, t = bid & 63;
  int c0 = (t >> 4) << 6;
  int p0 = (t & 15) << 6;
  __shared__ float tile[64][65];
  int tid = threadIdx.x;
  int lo = tid & 63, hi = tid >> 6;
  const float* xp = x + ((size_t)b * DM + c0) * PP + p0;
#pragma unroll
  for (int rr = 0; rr < 16; ++rr) {
    int c = rr * 4 + hi;
    tile[c][lo] = xp[(size_t)c * PP + lo];
  }
  __syncthreads();
  if (tid < 64) {
    float s = 0.f;
#pragma unroll
    for (int j = 0; j < 64; ++j) s += tile[tid][j];
    psum[((size_t)b * DM + c0 + tid) * 16 + (t & 15)] = s;
  }
  u16* op = xbt + ((size_t)b * PP + p0) * DM + c0;
#pragma unroll
  for (int rr = 0; rr < 16; ++rr) {
    int p = rr * 4 + hi;
    op[(size_t)p * DM + lo] = f2bf(tile[lo][p]);
  }
}

__global__ __launch_bounds__(256) void k_xbar(const float* __restrict__ psum,
                                              float* __restrict__ xbar) {
  int i = blockIdx.x * 256 + threadIdx.x;
  const float* p = psum + (size_t)i * 16;
  float s = 0.f;
#pragma unroll
  for (int j = 0; j < 16; ++j) s += p[j];
  xbar[i] = s;
}

__global__ __launch_bounds__(256) void k_wconv(const float* __restrict__ q_w,
                                               const float* __restrict__ k_w,
                                               u16* __restrict__ q_wb,
                                               u16* __restrict__ k_wb) {
  int i = blockIdx.x * 256 + threadIdx.x;
  q_wb[i] = f2bf(q_w[i]);
  k_wb[i] = f2bf(k_w[i]);
}

// ---------------------------------------------------------------------------
// 256x256-tile NT GEMM, 8 waves (2M x 4N), BK=32, 2 phases per K-tile,
// counted vmcnt (never 0 mid-loop), setprio around MFMA clusters,
// quarter-chunk XOR swizzle (stage-source + read, involution).
// Per-wave output 128x64 (8x4 fragments).
// ---------------------------------------------------------------------------
#define MODE_K   0
#define MODE_Q   1
#define MODE_OUT 2

template<int MODE>
__global__ __launch_bounds__(512, 1) void k_gemm(
    const u16* __restrict__ A, long sA,
    const u16* __restrict__ Bm, long sB,
    int N, int K,
    const float* __restrict__ bias_gm,   // MODE_K: k_b
    const float* __restrict__ bias_gn,   // MODE_Q: q_b
    void* __restrict__ out0, long sOut, int ldo,
    float* __restrict__ aux0,            // K: kpart(float2), Q: qpart, OUT: colscale
    float* __restrict__ aux1,            // K: kcen
    const float* __restrict__ obias)     // OUT: per (b,gm)
{
  int b = blockIdx.y;
  int ntn = N >> 8;
  int tm = blockIdx.x / ntn, tn = blockIdx.x % ntn;
  const u16* Ab = A + (size_t)b * sA + ((size_t)(tm << 8)) * K;
  const u16* Bb = Bm + (size_t)b * sB + ((size_t)(tn << 8)) * K;
  __shared__ u16 As[2][256 * 32];   // 2 x 16 KB
  __shared__ u16 Bs[2][256 * 32];   // 2 x 16 KB
  int tid = threadIdx.x;
  int lane = tid & 63, wid = tid >> 6;   // 8 waves
  int wr = wid >> 2, wc = wid & 3;       // 2 M-waves x 4 N-waves
  int rl = lane & 15, hi = lane >> 4;

  floatx4 acc[8][4];
#pragma unroll
  for (int m = 0; m < 8; ++m)
#pragma unroll
    for (int n = 0; n < 4; ++n) acc[m][n] = (floatx4){0.f, 0.f, 0.f, 0.f};

  // staging geometry: granule = 512 thr x 16B = 8 KB = 128 rows x 32 k (bf16)
  // chunk for this thread: row-within-granule = tid>>2, quarter = tid&3
  int srow = tid >> 2;
  int ssw = ((tid & 3) ^ ((srow >> 1) & 3)) << 3;  // swizzled source k-offset (elems)

  auto STGA = [&](int t, int g) {
    int row = (g << 7) + srow;
    __builtin_amdgcn_global_load_lds(
        (const __attribute__((address_space(1))) void*)(Ab + (size_t)row * K + (t << 5) + ssw),
        (__attribute__((address_space(3))) void*)(As[t & 1] + (((g << 9) + tid) << 3)),
        16, 0, 0);
  };
  auto STGB = [&](int t, int g) {
    int row = (g << 7) + srow;
    __builtin_amdgcn_global_load_lds(
        (const __attribute__((address_space(1))) void*)(Bb + (size_t)row * K + (t << 5) + ssw),
        (__attribute__((address_space(3))) void*)(Bs[t & 1] + (((g << 9) + tid) << 3)),
        16, 0, 0);
  };

  int NT = K >> 5;
  // prologue: tile0 fully (A0,A1,B0,B1), tile1 A-granules
  STGA(0, 0); STGA(0, 1); STGB(0, 0); STGB(0, 1);
  STGA(1, 0); STGA(1, 1);

  for (int t = 0; t < NT; ++t) {
    int cb = t & 1;
    // tile boundary: own loads for tile t landed (all waves, via barrier);
    // keep next tile's 2 A-granule loads in flight (counted vmcnt).
    if (t == NT - 1) asm volatile("s_waitcnt vmcnt(0)" ::: "memory");
    else             asm volatile("s_waitcnt vmcnt(2)" ::: "memory");
    __builtin_amdgcn_s_barrier();

    // ---- phase 0: 12 ds_reads + stage B(t+1) + MFMA lower-half ----
    short8 bfr[4], af[8];
#pragma unroll
    for (int n = 0; n < 4; ++n) {
      int rb = wc * 64 + n * 16 + rl;
      bfr[n] = *(const short8*)(Bs[cb] + rb * 32 + ((hi ^ ((rb >> 1) & 3)) << 3));
    }
#pragma unroll
    for (int m = 0; m < 8; ++m) {
      int ra = wr * 128 + m * 16 + rl;
      af[m] = *(const short8*)(As[cb] + ra * 32 + ((hi ^ ((ra >> 1) & 3)) << 3));
    }
    if (t + 1 < NT) { STGB(t + 1, 0); STGB(t + 1, 1); }
    __builtin_amdgcn_s_barrier();
    asm volatile("s_waitcnt lgkmcnt(0)" ::: "memory");  // all reads retired -> buf[cb] dead
    __builtin_amdgcn_sched_barrier(0);
    __builtin_amdgcn_s_setprio(1);
#pragma unroll
    for (int m = 0; m < 4; ++m)
#pragma unroll
      for (int n = 0; n < 4; ++n)
        acc[m][n] = __builtin_amdgcn_mfma_f32_16x16x32_bf16(af[m], bfr[n], acc[m][n], 0, 0, 0);
    __builtin_amdgcn_s_setprio(0);
    __builtin_amdgcn_s_barrier();

    // ---- phase 1: stage A(t+2) into buf[cb] (legal: reads retired) + MFMA upper ----
    if (t + 2 < NT) { STGA(t + 2, 0); STGA(t + 2, 1); }
    __builtin_amdgcn_s_setprio(1);
#pragma unroll
    for (int m = 4; m < 8; ++m)
#pragma unroll
      for (int n = 0; n < 4; ++n)
        acc[m][n] = __builtin_amdgcn_mfma_f32_16x16x32_bf16(af[m], bfr[n], acc[m][n], 0, 0, 0);
    __builtin_amdgcn_s_setprio(0);
  }

  int gmbase = (tm << 8) + wr * 128;
  int gnbase = (tn << 8) + wc * 64;

  if (MODE == MODE_K) {
    if (tn == 1 || tn == 2) {
#pragma unroll
      for (int n = 0; n < 4; ++n) {
        int gn = gnbase + n * 16 + rl;
        int j = (gn == 495) ? 0 : (gn == 496) ? 1 : (gn == 527) ? 2 : (gn == 528) ? 3 : -1;
        if (j >= 0) {
#pragma unroll
          for (int m = 0; m < 8; ++m)
#pragma unroll
            for (int r = 0; r < 4; ++r) {
              int gm = gmbase + m * 16 + hi * 4 + r;
              aux1[((size_t)(b * 512) + gm) * 4 + j] = acc[m][n][r] + bias_gm[gm];
            }
        }
      }
    }
    float2* kp = (float2*)aux0;
#pragma unroll
    for (int m = 0; m < 8; ++m)
#pragma unroll
      for (int r = 0; r < 4; ++r) {
        int gm = gmbase + m * 16 + hi * 4 + r;
        float kb = bias_gm[gm];
        float v0 = acc[m][0][r] + kb, v1 = acc[m][1][r] + kb;
        float v2 = acc[m][2][r] + kb, v3 = acc[m][3][r] + kb;
        float mx = fmaxf(fmaxf(v0, v1), fmaxf(v2, v3));
        mx = red16_max(mx);
        float se = __expf(v0 - mx) + __expf(v1 - mx) + __expf(v2 - mx) + __expf(v3 - mx);
        se = red16_sum(se);
        if (rl == 0)
          kp[((size_t)(b * 512) + gm) * 16 + tn * 4 + wc] = make_float2(mx, se);
      }
  }

  if (MODE == MODE_Q) {
    float qb[4];
#pragma unroll
    for (int n = 0; n < 4; ++n) qb[n] = bias_gn[gnbase + n * 16 + rl];
    u16* qe = (u16*)out0;
#pragma unroll
    for (int m = 0; m < 8; ++m)
#pragma unroll
      for (int r = 0; r < 4; ++r) {
        int gm = gmbase + m * 16 + hi * 4 + r;
        float rs = 0.f;
#pragma unroll
        for (int n = 0; n < 4; ++n) {
          float e = __expf(acc[m][n][r] + qb[n]);
          rs += e;
          qe[(size_t)b * sOut + (size_t)gm * ldo + gnbase + n * 16 + rl] = f2bf(e);
        }
        rs = red16_sum(rs);
        if (rl == 0)
          aux0[((size_t)(b * 1024) + gm) * 8 + tn * 4 + wc] = rs;
      }
  }

  if (MODE == MODE_OUT) {
    float cs[4];
#pragma unroll
    for (int n = 0; n < 4; ++n) cs[n] = aux0[b * 1024 + gnbase + n * 16 + rl];
    float* op = (float*)out0;
#pragma unroll
    for (int m = 0; m < 8; ++m)
#pragma unroll
      for (int r = 0; r < 4; ++r) {
        int gm = gmbase + m * 16 + hi * 4 + r;
        float ob = obias[b * 256 + gm];
#pragma unroll
        for (int n = 0; n < 4; ++n)
          op[(size_t)b * sOut + (size_t)gm * ldo + gnbase + n * 16 + rl] =
              acc[m][n][r] * cs[n] + ob;
      }
  }
}

// ---------------------------------------------------------------------------
// Combine K partials: per (b,o) global max + expsum; kcexp; S[b]
// ---------------------------------------------------------------------------
__global__ __launch_bounds__(512) void k_combine(const float2* __restrict__ kpart,
                                                 const float* __restrict__ kcen,
                                                 float* __restrict__ kcexp,
                                                 float* __restrict__ Sb) {
  int b = blockIdx.x, o = threadIdx.x;
  const float2* kp = kpart + ((size_t)(b * 512) + o) * 16;
  float mx = kp[0].x;
#pragma unroll
  for (int t = 1; t < 16; ++t) mx = fmaxf(mx, kp[t].x);
  float se = 0.f;
#pragma unroll
  for (int t = 0; t < 16; ++t) se += kp[t].y * __expf(kp[t].x - mx);
  const float* kc = kcen + ((size_t)(b * 512) + o) * 4;
#pragma unroll
  for (int j = 0; j < 4; ++j)
    kcexp[((size_t)(b * 512) + o) * 4 + j] = __expf(kc[j] - mx);
  __shared__ float sd[512];
  sd[o] = se; __syncthreads();
  for (int k = 256; k > 0; k >>= 1) { if (o < k) sd[o] += sd[o + k]; __syncthreads(); }
  if (o == 0) Sb[b] = sd[0];
}

__global__ __launch_bounds__(256) void k_qscale(const float* __restrict__ qpart,
                                                float* __restrict__ colscale) {
  int i = blockIdx.x * 256 + threadIdx.x;
  const float4* p = (const float4*)(qpart + (size_t)i * 8);
  float4 a = p[0], c = p[1];
  colscale[i] = 1.f / (a.x + a.y + a.z + a.w + c.x + c.y + c.z + c.w);
}

__global__ __launch_bounds__(256) void k_vc(const u16* __restrict__ xbt,
                                            const float* __restrict__ v_w,
                                            const float* __restrict__ v_b,
                                            float* __restrict__ Vc) {
  int b = blockIdx.x, vo = threadIdx.x;
  const int cp[4] = {495, 496, 527, 528};
  float acc[4];
  float vb = v_b[vo];
#pragma unroll
  for (int j = 0; j < 4; ++j) acc[j] = vb;
  for (int cc = 0; cc < 256; cc += 4) {
    float4 w = *(const float4*)(v_w + (size_t)vo * 256 + cc);
#pragma unroll
    for (int j = 0; j < 4; ++j) {
      const u16* xr = xbt + ((size_t)b * PP + cp[j]) * DM + cc;
      acc[j] += w.x * bf2f(xr[0]) + w.y * bf2f(xr[1]) + w.z * bf2f(xr[2]) + w.w * bf2f(xr[3]);
    }
  }
#pragma unroll
  for (int j = 0; j < 4; ++j) Vc[((size_t)b * 256 + vo) * 4 + j] = acc[j];
}

__global__ __launch_bounds__(256) void k_kvp(const float* __restrict__ kcexp,
                                             const float* __restrict__ Vc,
                                             const float* __restrict__ S,
                                             float* __restrict__ KVp) {
  int b = blockIdx.x >> 3, h = blockIdx.x & 7;
  float inv = 0.25f / S[b];
  int tid = threadIdx.x;
#pragma unroll
  for (int j = 0; j < 8; ++j) {
    int idx = j * 256 + tid;
    int q = idx >> 5, v = idx & 31;
    const float* kc = kcexp + ((size_t)b * 512 + h * 64 + q) * 4;
    const float* vv = Vc + ((size_t)b * 256 + h * 32 + v) * 4;
    KVp[(((size_t)(b * 8 + h) * 64 + q) * 32) + v] =
        inv * (kc[0] * vv[0] + kc[1] * vv[1] + kc[2] * vv[2] + kc[3] * vv[3]);
  }
}

__global__ __launch_bounds__(256) void k_lnbias(const float* __restrict__ xbar,
                                                const float* __restrict__ bias_w,
                                                const float* __restrict__ bias_b,
                                                const float* __restrict__ ln_g,
                                                const float* __restrict__ ln_b,
                                                const float* __restrict__ uni_w,
                                                const float* __restrict__ uni_b,
                                                float* __restrict__ obias) {
  int b = blockIdx.x, o = threadIdx.x;
  const float* xb = xbar + (size_t)b * 256;
  float acc = 0.f;
  for (int cc = 0; cc < 256; cc += 4) {
    float4 w = *(const float4*)(bias_w + (size_t)o * 256 + cc);
    acc += w.x * xb[cc] + w.y * xb[cc + 1] + w.z * xb[cc + 2] + w.w * xb[cc + 3];
  }
  float bf_ = acc * (1.f / 1024.f) + bias_b[o];
  __shared__ float sd[256];
  sd[o] = bf_; __syncthreads();
  for (int k = 128; k > 0; k >>= 1) { if (o < k) sd[o] += sd[o + k]; __syncthreads(); }
  float mu = sd[0] / 256.f; __syncthreads();
  sd[o] = bf_ * bf_; __syncthreads();
  for (int k = 128; k > 0; k >>= 1) { if (o < k) sd[o] += sd[o + k]; __syncthreads(); }
  float var = sd[0] / 256.f - mu * mu; __syncthreads();
  float nb = (bf_ - mu) * rsqrtf(var + 1e-5f) * ln_g[o] + ln_b[o];
  sd[o] = nb; __syncthreads();
  float ob = uni_b[o];
  for (int vo = 0; vo < 256; ++vo) ob += uni_w[(size_t)o * 256 + vo] * sd[vo];
  obias[(size_t)b * 256 + o] = ob;
}

// Wc[b][m][h*64+q] = sum_v uni_w[m][h*32+v] * KVp[b][h][q][v]
__global__ __launch_bounds__(256) void k_wc(const float* __restrict__ KVp,
                                            const float* __restrict__ uni_w,
                                            u16* __restrict__ Wc) {
  int b = blockIdx.x >> 3;
  int h = blockIdx.x & 7;
  __shared__ float kv[64 * 32];
  int tid = threadIdx.x;
  const float* src = KVp + (size_t)b * 16384 + (size_t)h * 2048;
#pragma unroll
  for (int j = 0; j < 8; ++j) kv[j * 256 + tid] = src[j * 256 + tid];
  __syncthreads();

  int m = tid;
  float uw[32];
  const float* uwp = uni_w + (size_t)m * 256 + h * 32;
#pragma unroll
  for (int v = 0; v < 32; v += 4) {
    float4 w = *(const float4*)(uwp + v);
    uw[v] = w.x; uw[v + 1] = w.y; uw[v + 2] = w.z; uw[v + 3] = w.w;
  }

  union { uint4 o4[8]; u16 os[64]; } ob;
#pragma unroll
  for (int q = 0; q < 64; ++q) {
    const float* kp = kv + q * 32;
    float s = 0.f;
#pragma unroll
    for (int v = 0; v < 32; ++v) s += uw[v] * kp[v];
    ob.os[q] = f2bf(s);
  }
  uint4* dst = (uint4*)(Wc + ((size_t)(b * 256 + m)) * 512 + h * 64);
#pragma unroll
  for (int j = 0; j < 8; ++j) dst[j] = ob.o4[j];
}

// ---------------------------------------------------------------------------
extern "C" void kernel_launch(void* const* d_in, const int* in_sizes, int n_in,
                              void* d_out, int out_size, void* d_ws, size_t ws_size,
                              hipStream_t stream) {
  const float* x      = (const float*)d_in[0];
  const float* q_w    = (const float*)d_in[1];
  const float* q_b    = (const float*)d_in[2];
  const float* k_w    = (const float*)d_in[3];
  const float* k_b    = (const float*)d_in[4];
  const float* v_w    = (const float*)d_in[5];
  const float* v_b    = (const float*)d_in[6];
  const float* bias_w = (const float*)d_in[7];
  const float* bias_b = (const float*)d_in[8];
  const float* ln_g   = (const float*)d_in[9];
  const float* ln_b   = (const float*)d_in[10];
  const float* uni_w  = (const float*)d_in[11];
  const float* uni_b  = (const float*)d_in[12];

  char* ws = (char*)d_ws;
  size_t off = 0;
  auto alloc = [&](size_t bytes) {
    void* p = ws + off;
    off = (off + bytes + 255) & ~(size_t)255;
    return p;
  };
  u16*   xbt   = (u16*)  alloc(64ull * 1024 * 256 * 2);   // x^T bf16
  u16*   qexp  = (u16*)  alloc(64ull * 1024 * 512 * 2);   // exp(Q^T) bf16
  u16*   wcb   = (u16*)  alloc(64ull * 256 * 512 * 2);    // folded uni_w∘KVp
  u16*   q_wb  = (u16*)  alloc(131072ull * 2);
  u16*   k_wb  = (u16*)  alloc(131072ull * 2);
  float* psum  = (float*)alloc(64ull * 256 * 16 * 4);
  float* xbar  = (float*)alloc(64ull * 256 * 4);
  float* kpart = (float*)alloc(32768ull * 16 * 8);        // float2 per (row, tn*4+wc)
  float* kcen  = (float*)alloc(32768ull * 4 * 4);
  float* qpart = (float*)alloc(65536ull * 8 * 4);
  float* cscal = (float*)alloc(65536ull * 4);
  float* Sb    = (float*)alloc(64ull * 4);
  float* kcexp = (float*)alloc(64ull * 512 * 4 * 4);
  float* vc    = (float*)alloc(64ull * 256 * 4 * 4);
  float* kvp   = (float*)alloc(64ull * 8 * 64 * 32 * 4);
  float* obias = (float*)alloc(64ull * 256 * 4);
  (void)ws_size; (void)in_sizes; (void)n_in; (void)out_size;

  k_wconv<<<512, 256, 0, stream>>>(q_w, k_w, q_wb, k_wb);
  k_transpose<<<4096, 256, 0, stream>>>(x, xbt, psum);
  k_xbar<<<64, 256, 0, stream>>>(psum, xbar);

  // K projection + fused stats: M=512(o), N=1024(p), K=256 — no C write
  k_gemm<MODE_K><<<dim3(8, 64), 512, 0, stream>>>(
      k_wb, 0L, xbt, 262144L, 1024, 256,
      k_b, nullptr, nullptr, 0L, 0, kpart, kcen, nullptr);
  // Q projection + fused exp: M=1024(p), N=512(o), K=256 — qexp bf16
  k_gemm<MODE_Q><<<dim3(8, 64), 512, 0, stream>>>(
      xbt, 262144L, q_wb, 0L, 512, 256,
      nullptr, q_b, (void*)qexp, 524288L, 512, qpart, nullptr, nullptr);

  k_combine<<<64, 512, 0, stream>>>((const float2*)kpart, kcen, kcexp, Sb);
  k_qscale<<<256, 256, 0, stream>>>(qpart, cscal);
  k_vc<<<64, 256, 0, stream>>>(xbt, v_w, v_b, vc);
  k_kvp<<<512, 256, 0, stream>>>(kcexp, vc, Sb, kvp);
  k_lnbias<<<64, 256, 0, stream>>>(xbar, bias_w, bias_b, ln_g, ln_b, uni_w, uni_b, obias);
  k_wc<<<512, 256, 0, stream>>>(kvp, uni_w, wcb);

  // Final GEMM: out[b][m][p] = (Wc @ Qexp^T) * colscale[p] + obias[m]
  k_gemm<MODE_OUT><<<dim3(4, 64), 512, 0, stream>>>(
      wcb, 131072L, qexp, 524288L, 1024, 512,
      nullptr, nullptr, d_out, 262144L, 1024, cscal, nullptr, obias);
}